// Round 6
// baseline (475.603 us; speedup 1.0000x reference)
//
#include <hip/hip_runtime.h>

// Problem constants (GCN_61065845014917)
#define B_   4
#define C_   1024
#define D_   768
#define H_   12
#define E_   32
#define K_   2
#define S_   24
#define V_   8
#define P_   512
#define NT_  256
#define EMB_ 768
#define BLK_ 64
#define NL_  97
#define DNT_ 1024     // D+NT
#define KHT_ 1792     // 2D+NT
#define KBIL_ 49152   // EMB*BLK
#define NPAD_ 128     // NL padded for MFMA
#define NGIC_ 24      // bilinear partial slabs (12 g x 2 i-halves)

typedef __bf16 bf16x8 __attribute__((ext_vector_type(8)));
typedef float  f32x4  __attribute__((ext_vector_type(4)));

__device__ __forceinline__ float b2f(unsigned short u) {
    return (float)__builtin_bit_cast(__bf16, u);
}
__device__ __forceinline__ unsigned short f2b(float f) {
    return __builtin_bit_cast(unsigned short, (__bf16)f);   // RNE
}
// dtype-dispatched input load / output store (isf=1: f32 buffers, isf=0: bf16)
__device__ __forceinline__ float ld_in(const void* p, size_t i, int isf) {
    return isf ? ((const float*)p)[i] : b2f(((const unsigned short*)p)[i]);
}
__device__ __forceinline__ void st_out(void* p, size_t i, float v, int isf) {
    if (isf) ((float*)p)[i] = v;
    else     ((unsigned short*)p)[i] = f2b(v);
}
// per-wave inline dtype probe: 64 even-index ushorts of sequence_output.
__device__ __forceinline__ int probe_isf(const void* seq) {
    unsigned short u = ((const unsigned short*)seq)[2 * (threadIdx.x & 63)];
    int huge = !(fabsf(b2f(u)) <= 1e10f);          // catches NaN
    unsigned long long zb = __ballot(u == 0);
    return __any(huge) || (__popcll(zb) > 56);
}

// ---------------------------------------------------------------------------
// K1 fused prep: [0,256) gather, [256,1792) eatt, [1792,2560) t_seq,
//                [2560,3232) t_w, [3232,4000) t_bil(fragment-order W2)
#define PREP_GATHER 256
#define PREP_EATT   (PREP_GATHER + B_*E_*H_)     // +1536 -> 1792
#define PREP_TSEQ   (PREP_EATT + 768)            // -> 2560
#define PREP_TW     (PREP_TSEQ + 672)            // -> 3232
#define PREP_TBIL   (PREP_TW + 768)              // -> 4000

__global__ __launch_bounds__(256) void k_prep(
    const void* __restrict__ seq, const void* __restrict__ att,
    const int* __restrict__ epos, const int* __restrict__ spos,
    const int* __restrict__ vpos, const void* __restrict__ ntype,
    const void* __restrict__ Wh, const void* __restrict__ Wt_,
    const void* __restrict__ Wb,
    float* __restrict__ enth, unsigned short* __restrict__ e_att,
    unsigned short* __restrict__ seqT,
    unsigned short* __restrict__ WtH, unsigned short* __restrict__ WtT,
    unsigned short* __restrict__ WtB,
    void* __restrict__ outv, long long moff, long long soff, long long voff)
{
    __shared__ __align__(16) unsigned char smem[12544];
    int blk = blockIdx.x, tid = threadIdx.x;
    int isf = probe_isf(seq);
    if (blk < PREP_GATHER) {
        if (blk < B_ * E_) {
            int b = blk / E_, e = blk % E_;
            int i0 = epos[(b * E_ + e) * K_ + 0] + 1;
            int i1 = epos[(b * E_ + e) * K_ + 1] + 1;
            size_t r0 = ((size_t)b * C_ + i0) * D_;
            size_t r1 = ((size_t)b * C_ + i1) * D_;
            size_t m0 = (size_t)moff + ((size_t)(b * E_ * K_) + 2 * e) * D_;
            size_t m1 = m0 + D_;
            float* eh = enth + (size_t)(b * E_ + e) * DNT_;
            for (int d = tid; d < D_; d += 256) {
                float a = ld_in(seq, r0 + d, isf);
                float c = ld_in(seq, r1 + d, isf);
                st_out(outv, m0 + d, a, isf);
                st_out(outv, m1 + d, c, isf);
                float mx = fmaxf(a, c);
                eh[d] = mx + logf(expf(a - mx) + expf(c - mx));
            }
            size_t nt0 = (size_t)(b * E_ + e) * NT_;
            for (int j = tid; j < NT_; j += 256) eh[D_ + j] = ld_in(ntype, nt0 + j, isf);
        } else if (blk < B_ * E_ + B_ * S_) {
            int t = blk - B_ * E_; int b = t / S_, s = t % S_;
            int i = spos[b * S_ + s] + 1;
            size_t r = ((size_t)b * C_ + i) * D_;
            size_t o = (size_t)soff + (size_t)(b * S_ + s) * D_;
            for (int d = tid; d < D_; d += 256) st_out(outv, o + d, ld_in(seq, r + d, isf), isf);
        } else {
            int t = blk - B_ * E_ - B_ * S_; int b = t / V_, v = t % V_;
            int i = vpos[b * V_ + v] + 1;
            size_t r = ((size_t)b * C_ + i) * D_;
            size_t o = (size_t)voff + (size_t)(b * V_ + v) * D_;
            for (int d = tid; d < D_; d += 256) st_out(outv, o + d, ld_in(seq, r + d, isf), isf);
        }
    } else if (blk < PREP_EATT) {
        int t = blk - PREP_GATHER;
        int b = t / (E_ * H_); int r = t % (E_ * H_); int e = r / H_; int h = r % H_;
        int i0 = epos[(b * E_ + e) * K_ + 0] + 1;
        int i1 = epos[(b * E_ + e) * K_ + 1] + 1;
        size_t a0 = (((size_t)b * H_ + h) * C_ + i0) * C_;
        size_t a1 = (((size_t)b * H_ + h) * C_ + i1) * C_;
        unsigned short* o = e_att + (((size_t)(b * E_ + e)) * H_ + h) * C_;
        for (int c = tid; c < C_; c += 256)
            o[c] = f2b(0.5f * (ld_in(att, a0 + c, isf) + ld_in(att, a1 + c, isf)));
    } else if (blk < PREP_TSEQ) {
        int t = blk - PREP_EATT;                 // b*192 + ct*12 + dt
        int b = t / 192; int r = t % 192; int ct = r / 12; int dt = r % 12;
        typedef unsigned short row65[65];
        row65* tile = (row65*)smem;
        for (int idx = tid; idx < 4096; idx += 256) {
            int cc = idx >> 6, dd = idx & 63;
            tile[cc][dd] = f2b(ld_in(seq, ((size_t)b * C_ + ct * 64 + cc) * D_ + dt * 64 + dd, isf));
        }
        __syncthreads();
        for (int idx = tid; idx < 4096; idx += 256) {
            int dd = idx >> 6, cc = idx & 63;
            seqT[((size_t)b * D_ + dt * 64 + dd) * C_ + ct * 64 + cc] = tile[cc][dd];
        }
    } else if (blk < PREP_TW) {
        int t = blk - PREP_TSEQ;                 // mat*336 + kt*12 + nt
        int mat = t / 336; int r = t % 336; int kt = r / 12; int nt = r % 12;
        const void* in = mat ? Wt_ : Wh;
        unsigned short* out = mat ? WtT : WtH;
        typedef unsigned short row65[65];
        row65* tile = (row65*)smem;
        for (int idx = tid; idx < 4096; idx += 256) {
            int kk = idx >> 6, nn = idx & 63;
            tile[kk][nn] = f2b(ld_in(in, ((size_t)kt * 64 + kk) * EMB_ + nt * 64 + nn, isf));
        }
        __syncthreads();
        for (int idx = tid; idx < 4096; idx += 256) {
            int nn = idx >> 6, kk = idx & 63;
            out[((size_t)nt * 64 + nn) * KHT_ + kt * 64 + kk] = tile[kk][nn];
        }
    } else {
        // t_bil: W2 in MFMA-fragment order (see k_bil). One (g,i) per block.
        // W2[((g*8 + w)*64 + i)*1024 + jh*512 + q*128 + l15*8 + e]
        //   = Wb[kflat = g*4096 + i*64 + jh*32 + q*8 + e][n = w*16 + l15]
        int t = blk - PREP_TW;                   // 768 blocks: one (g, i) each
        int g = t >> 6, i = t & 63;
        unsigned short* raw = (unsigned short*)smem;   // [64 j][97 n]
        size_t src0 = ((size_t)g * 4096 + (size_t)i * 64) * NL_;
        for (int idx = tid; idx < 64 * NL_; idx += 256)
            raw[idx] = f2b(ld_in(Wb, src0 + idx, isf));
        __syncthreads();
        for (int idx = tid; idx < 8192; idx += 256) {
            int w = idx >> 10, o = idx & 1023;
            int jh = o >> 9, q = (o >> 7) & 3, l15 = (o >> 3) & 15, e = o & 7;
            int j = jh * 32 + q * 8 + e;
            int n = w * 16 + l15;
            unsigned short v = (n < NL_) ? raw[j * NL_ + n] : (unsigned short)0;
            WtB[(((size_t)(g * 8 + w) * 64 + i) << 10) + o] = v;
        }
    }
}

// ---------------------------------------------------------------------------
// K2 fused mid: [0,2048) htatt, [2048,4096) xbuild
__global__ __launch_bounds__(256) void k_mid(
    const unsigned short* __restrict__ e_att, const float* __restrict__ enth,
    const int* __restrict__ hts,
    unsigned short* __restrict__ htb,
    unsigned short* __restrict__ Xh, unsigned short* __restrict__ Xt)
{
    __shared__ float red[4];
    int blk = blockIdx.x, tid = threadIdx.x;
    if (blk < B_ * P_) {
        int b = blk >> 9;
        int he = hts[blk * 2 + 0], te = hts[blk * 2 + 1];
        const unsigned short* ph = e_att + (size_t)(b * E_ + he) * H_ * C_;
        const unsigned short* pt = e_att + (size_t)(b * E_ + te) * H_ * C_;
        float v[4]; float ls = 0.f;
        for (int ci = 0; ci < 4; ci++) {
            int c = tid + (ci << 8);
            float acc = 0.f;
#pragma unroll
            for (int h = 0; h < H_; h++) acc += b2f(ph[h * C_ + c]) * b2f(pt[h * C_ + c]);
            acc *= (1.0f / (float)H_);
            v[ci] = acc; ls += acc;
        }
        for (int off = 32; off > 0; off >>= 1) ls += __shfl_down(ls, off, 64);
        if ((tid & 63) == 0) red[tid >> 6] = ls;
        __syncthreads();
        float inv = 1.0f / (red[0] + red[1] + red[2] + red[3] + 1e-5f);
        for (int ci = 0; ci < 4; ci++)
            htb[((size_t)blk << 10) + tid + (ci << 8)] = f2b(v[ci] * inv);
    } else {
        int m = blk - B_ * P_; int b = m >> 9;
        int eh = hts[m * 2 + 0], et = hts[m * 2 + 1];
        const float* sh = enth + (size_t)(b * E_ + eh) * DNT_;
        const float* st = enth + (size_t)(b * E_ + et) * DNT_;
        for (int k = tid; k < DNT_; k += 256) {
            Xh[(size_t)m * KHT_ + k] = f2b(sh[k]);
            Xt[(size_t)m * KHT_ + k] = f2b(st[k]);
        }
    }
}

// ---------------------------------------------------------------------------
// bf16 MFMA GEMM v2: 128m x 64n tile, K-step 64, 4 waves (2m x 2n), each wave
// 64m x 32n = 4x2 subtiles -> 16 MFMA per K64-step between ONE barrier pair
// (4x the MFMA:barrier ratio of the old 64^2/K32 kernel -- R5 post-mortem put
// the ht GEMM at ~40 us, barrier-bound). LDS rows padded to 72 elems
// (144 B = 36 words -> read conflict 2-way = free). Plain VGPR staging
// (R2 lesson: no global_load_lds here).
// zmode 0 (rs): z = batch; epilogue writes bf16 into Xh/Xt cols DNT_+n.
// zmode 1 (ht): z = mat (0=head,1=tail); epilogue bf16 tanh(acc+bias) -> oY.
// nsteps = K/64.
__global__ __launch_bounds__(256) void k_gemm(
    const unsigned short* __restrict__ A0, const unsigned short* __restrict__ A1,
    const unsigned short* __restrict__ B0, const unsigned short* __restrict__ B1,
    long long lda, long long ldb, long long sAz, long long sBz,
    int nsteps, int zmode,
    const void* __restrict__ bias0, const void* __restrict__ bias1,
    unsigned short* __restrict__ oY0, unsigned short* __restrict__ oY1,
    unsigned short* __restrict__ oX1, unsigned short* __restrict__ oX2,
    const void* __restrict__ seq)
{
    int n0 = blockIdx.x * 64, m0 = blockIdx.y * 128, z = blockIdx.z;
    const unsigned short* Ab; const unsigned short* Bb;
    unsigned short* oY = nullptr; const void* bias = nullptr;
    if (zmode == 0) {
        Ab = A0 + (size_t)z * sAz; Bb = B0 + (size_t)z * sBz;
    } else {
        Ab = z ? A1 : A0; Bb = z ? B1 : B0;
        oY = z ? oY1 : oY0; bias = z ? bias1 : bias0;
    }
    __shared__ __align__(16) unsigned short a_lds[128][72];
    __shared__ __align__(16) unsigned short b_lds[64][72];
    int tid = threadIdx.x, lane = tid & 63, w = tid >> 6;
    int wm = (w >> 1) * 64, wn = (w & 1) * 32, q = lane >> 4, l15 = lane & 15;

    f32x4 acc[4][2];
#pragma unroll
    for (int ms = 0; ms < 4; ++ms)
#pragma unroll
        for (int ns = 0; ns < 2; ++ns) acc[ms][ns] = (f32x4){0.f, 0.f, 0.f, 0.f};

    // staging map: A 1024 chunks (128 rows x 8), B 512 chunks (64 rows x 8)
    int arow[4], acol[4], brow[2], bcol[2];
    const unsigned short* pa[4]; const unsigned short* pb[2];
#pragma unroll
    for (int k2 = 0; k2 < 4; ++k2) {
        int c = tid + k2 * 256;
        arow[k2] = c >> 3; acol[k2] = (c & 7) * 8;
        pa[k2] = Ab + (size_t)(m0 + arow[k2]) * lda + acol[k2];
    }
#pragma unroll
    for (int k2 = 0; k2 < 2; ++k2) {
        int c = tid + k2 * 256;
        brow[k2] = c >> 3; bcol[k2] = (c & 7) * 8;
        pb[k2] = Bb + (size_t)(n0 + brow[k2]) * ldb + bcol[k2];
    }
    int4 ra[4], rb[2];
#pragma unroll
    for (int k2 = 0; k2 < 4; ++k2) ra[k2] = *(const int4*)pa[k2];
#pragma unroll
    for (int k2 = 0; k2 < 2; ++k2) rb[k2] = *(const int4*)pb[k2];

    for (int ks = 0; ks < nsteps; ks++) {
        __syncthreads();
#pragma unroll
        for (int k2 = 0; k2 < 4; ++k2) *(int4*)&a_lds[arow[k2]][acol[k2]] = ra[k2];
#pragma unroll
        for (int k2 = 0; k2 < 2; ++k2) *(int4*)&b_lds[brow[k2]][bcol[k2]] = rb[k2];
        __syncthreads();
        if (ks + 1 < nsteps) {
#pragma unroll
            for (int k2 = 0; k2 < 4; ++k2) ra[k2] = *(const int4*)(pa[k2] + (size_t)(ks + 1) * 64);
#pragma unroll
            for (int k2 = 0; k2 < 2; ++k2) rb[k2] = *(const int4*)(pb[k2] + (size_t)(ks + 1) * 64);
        }
#pragma unroll
        for (int kk = 0; kk < 2; ++kk) {
            bf16x8 af[4], bfr[2];
#pragma unroll
            for (int ms = 0; ms < 4; ++ms)
                af[ms] = *(const bf16x8*)&a_lds[wm + ms * 16 + l15][kk * 32 + q * 8];
#pragma unroll
            for (int ns = 0; ns < 2; ++ns)
                bfr[ns] = *(const bf16x8*)&b_lds[wn + ns * 16 + l15][kk * 32 + q * 8];
#pragma unroll
            for (int ms = 0; ms < 4; ++ms)
#pragma unroll
                for (int ns = 0; ns < 2; ++ns)
                    acc[ms][ns] = __builtin_amdgcn_mfma_f32_16x16x32_bf16(af[ms], bfr[ns], acc[ms][ns], 0, 0, 0);
        }
    }
    int isf = (zmode == 1) ? probe_isf(seq) : 0;
#pragma unroll
    for (int ms = 0; ms < 4; ++ms)
#pragma unroll
        for (int ns = 0; ns < 2; ++ns) {
            int gmb = m0 + wm + ms * 16 + q * 4;
            int gn  = n0 + wn + ns * 16 + l15;
            if (zmode == 0) {
#pragma unroll
                for (int r = 0; r < 4; r++) {
                    unsigned short v = f2b(acc[ms][ns][r]);
                    size_t o = (size_t)(z * P_ + gmb + r) * KHT_ + DNT_ + gn;
                    oX1[o] = v; oX2[o] = v;
                }
            } else {
                float bv = ld_in(bias, gn, isf);
#pragma unroll
                for (int r = 0; r < 4; r++)
                    oY[(size_t)(gmb + r) * EMB_ + gn] = f2b(tanhf(acc[ms][ns][r] + bv));
            }
        }
}

// ---------------------------------------------------------------------------
// Grouped bilinear v7: v6's fragment-ordered streaming W + depth-4 register
// prefetch (R5 post-mortem: dist-2 gave only ~250cy slack at observed per-iter
// pace -- marginal vs L2 ~250cy latency; depth-4 gives ~500cy, fully hiding).
// Static named slots (runtime-indexed vector arrays would spill, rule #20).
__global__ __launch_bounds__(512) void k_bil(
    const unsigned short* __restrict__ hsB, const unsigned short* __restrict__ tsB,
    const unsigned short* __restrict__ W2, float* __restrict__ logitsP)
{
    // 768 blocks = 8 XCDs x 96; per XCD: 3 (g,ic) combos x 32 m-tiles
    int bid = blockIdx.x;
    int lin = (bid & 7) * 96 + (bid >> 3);
    int mt  = lin & 31;            // m-tile  [0,32)
    int gic = lin >> 5;            // [0,24)  (also the partial-slab index)
    int g   = gic >> 1;            // group   [0,12)
    int ic  = gic & 1;             // i-half  [0,2)
    int m0  = mt * 64;

    int tid = threadIdx.x, lane = tid & 63, w = tid >> 6;
    int q = lane >> 4, l15 = lane & 15;
    int ns = w * 16;               // wave-private n-subtile

    __shared__ __align__(16) unsigned short hsT[32][64];   // [i][m], 4 KB
    {
        int m = tid >> 3, i4 = (tid & 7) * 4;
        ushort4 hv = *(const ushort4*)&hsB[(size_t)(m0 + m) * EMB_ + g * 64 + ic * 32 + i4];
        hsT[i4 + 0][m] = hv.x; hsT[i4 + 1][m] = hv.y;
        hsT[i4 + 2][m] = hv.z; hsT[i4 + 3][m] = hv.w;
    }

    // ts A-fragments (invariant over i): 4 m-subtiles x 2 j-halves
    bf16x8 a[4][2];
#pragma unroll
    for (int ms = 0; ms < 4; ++ms)
#pragma unroll
        for (int jh = 0; jh < 2; ++jh)
            a[ms][jh] = *(const bf16x8*)&tsB[(size_t)(m0 + ms * 16 + l15) * EMB_
                                             + g * 64 + jh * 32 + q * 8];
    __syncthreads();

    // wave's W2 stream: chunk i is 1024 elems (2KB); wa at +lane*8, wb at +512
    const unsigned short* pw = W2 + (((size_t)(g * 8 + w) * 64 + ic * 32) << 10) + lane * 8;

    f32x4 acc[4];
#pragma unroll
    for (int ms = 0; ms < 4; ++ms) acc[ms] = (f32x4){0.f, 0.f, 0.f, 0.f};
    const f32x4 zf = {0.f, 0.f, 0.f, 0.f};

    // depth-4 software pipeline, static named slots
    bf16x8 w0a = *(const bf16x8*)(pw);
    bf16x8 w0b = *(const bf16x8*)(pw + 512);
    bf16x8 w1a = *(const bf16x8*)(pw + 1024);
    bf16x8 w1b = *(const bf16x8*)(pw + 1536);
    bf16x8 w2a = *(const bf16x8*)(pw + 2048);
    bf16x8 w2b = *(const bf16x8*)(pw + 2560);
    bf16x8 w3a = *(const bf16x8*)(pw + 3072);
    bf16x8 w3b = *(const bf16x8*)(pw + 3584);

#define BIL_STEP(ii, wa_, wb_)                                                             \
    do {                                                                                   \
        int ipre = (ii) + 4 <= 31 ? (ii) + 4 : 31;                                         \
        bf16x8 na = *(const bf16x8*)(pw + ((size_t)ipre << 10));                           \
        bf16x8 nb = *(const bf16x8*)(pw + ((size_t)ipre << 10) + 512);                     \
        f32x4 p[4];                                                                        \
        _Pragma("unroll")                                                                  \
        for (int ms = 0; ms < 4; ++ms) {                                                   \
            f32x4 t = __builtin_amdgcn_mfma_f32_16x16x32_bf16(a[ms][0], wa_, zf, 0, 0, 0); \
            p[ms]   = __builtin_amdgcn_mfma_f32_16x16x32_bf16(a[ms][1], wb_, t, 0, 0, 0);  \
        }                                                                                  \
        _Pragma("unroll")                                                                  \
        for (int ms = 0; ms < 4; ++ms) {                                                   \
            ushort4 hv = *(const ushort4*)&hsT[ii][ms * 16 + q * 4];                       \
            acc[ms][0] += b2f(hv.x) * p[ms][0];                                            \
            acc[ms][1] += b2f(hv.y) * p[ms][1];                                            \
            acc[ms][2] += b2f(hv.z) * p[ms][2];                                            \
            acc[ms][3] += b2f(hv.w) * p[ms][3];                                            \
        }                                                                                  \
        wa_ = na; wb_ = nb;                                                                \
    } while (0)

#pragma unroll 2
    for (int ii = 0; ii < 8; ++ii) {
        BIL_STEP(4 * ii + 0, w0a, w0b);
        BIL_STEP(4 * ii + 1, w1a, w1b);
        BIL_STEP(4 * ii + 2, w2a, w2b);
        BIL_STEP(4 * ii + 3, w3a, w3b);
    }
#undef BIL_STEP

    // conflict-free epilogue: each (mt,gic) block owns its [64][128] region
    float* outp = logitsP + ((size_t)gic * (B_ * P_) + m0) * NPAD_ + ns + l15;
#pragma unroll
    for (int ms = 0; ms < 4; ++ms)
#pragma unroll
        for (int r = 0; r < 4; ++r)
            outp[(size_t)(ms * 16 + q * 4 + r) * NPAD_] = acc[ms][r];
}

// ---------------------------------------------------------------------------
// final: reduce 24 bilinear partials + bias, n<97
__global__ __launch_bounds__(256) void k_fin(
    const float* __restrict__ logitsP, const void* __restrict__ b_bil,
    void* __restrict__ outv, const void* __restrict__ seq)
{
    int isf = probe_isf(seq);
    int idx = blockIdx.x * 256 + threadIdx.x;
    if (idx >= B_ * P_ * NL_) return;
    int m = idx / NL_, n = idx % NL_;
    float s = ld_in(b_bil, n, isf);
#pragma unroll
    for (int p = 0; p < NGIC_; ++p)
        s += logitsP[((size_t)p * (B_ * P_) + m) * NPAD_ + n];
    st_out(outv, idx, s, isf);
}

// ---------------------------------------------------------------------------
extern "C" void kernel_launch(void* const* d_in, const int* in_sizes, int n_in,
                              void* d_out, int out_size, void* d_ws, size_t ws_size,
                              hipStream_t stream)
{
    const void* seq    = d_in[0];
    const void* att    = d_in[1];
    const int*  epos   = (const int*)d_in[2];
    const int*  spos   = (const int*)d_in[3];
    const int*  vpos   = (const int*)d_in[4];
    const int*  hts    = (const int*)d_in[5];
    const void* ntype  = d_in[6];
    const void* W_head = d_in[7];
    const void* b_head = d_in[8];
    const void* W_tail = d_in[9];
    const void* b_tail = d_in[10];
    const void* W_bil  = d_in[11];
    const void* b_bil  = d_in[12];

    // output element offsets (dtype-agnostic)
    long long mention_off = (long long)B_ * P_ * NL_;
    long long sent_off    = mention_off + (long long)B_ * E_ * K_ * D_;
    long long virt_off    = sent_off + (long long)B_ * S_ * D_;

    // workspace carve (~75 MB)
    char* p = (char*)d_ws;
    auto alloc = [&](size_t bytes) { void* r = (void*)p; p += (bytes + 255) & ~(size_t)255; return r; };
    unsigned short* e_att   = (unsigned short*)alloc((size_t)B_ * E_ * H_ * C_ * 2);
    unsigned short* htb     = (unsigned short*)alloc((size_t)B_ * P_ * C_ * 2);
    unsigned short* seqT    = (unsigned short*)alloc((size_t)B_ * D_ * C_ * 2);
    unsigned short* WtH     = (unsigned short*)alloc((size_t)EMB_ * KHT_ * 2);
    unsigned short* WtT     = (unsigned short*)alloc((size_t)EMB_ * KHT_ * 2);
    unsigned short* WtB     = (unsigned short*)alloc((size_t)NPAD_ * KBIL_ * 2);  // W2, frag-order
    unsigned short* Xh      = (unsigned short*)alloc((size_t)B_ * P_ * KHT_ * 2);
    unsigned short* Xt      = (unsigned short*)alloc((size_t)B_ * P_ * KHT_ * 2);
    unsigned short* hsB     = (unsigned short*)alloc((size_t)B_ * P_ * EMB_ * 2);
    unsigned short* tsB     = (unsigned short*)alloc((size_t)B_ * P_ * EMB_ * 2);
    float*          logitsP = (float*)alloc((size_t)NGIC_ * B_ * P_ * NPAD_ * 4);  // 24 MB
    float*          enth    = (float*)alloc((size_t)B_ * E_ * DNT_ * 4);

    dim3 blk(256);
    k_prep<<<PREP_TBIL, blk, 0, stream>>>(
        seq, att, epos, spos, vpos, ntype, W_head, W_tail, W_bil,
        enth, e_att, seqT, WtH, WtT, WtB,
        d_out, mention_off, sent_off, virt_off);
    k_mid<<<2 * B_ * P_, blk, 0, stream>>>(e_att, enth, hts, htb, Xh, Xt);
    // rs GEMM: per batch [512 x 1024] @ [1024 x 768]^T -> X cols 1024..1791
    k_gemm<<<dim3(EMB_ / 64, P_ / 128, B_), blk, 0, stream>>>(
        htb, nullptr, seqT, nullptr, C_, C_,
        (long long)P_ * C_, (long long)D_ * C_, C_ / 64, 0,
        nullptr, nullptr, nullptr, nullptr, Xh, Xt, seq);
    // fused head+tail: [2048 x 1792] @ [1792 x 768]^T, tanh+bias -> bf16 hsB/tsB
    k_gemm<<<dim3(EMB_ / 64, (B_ * P_) / 128, 2), blk, 0, stream>>>(
        Xh, Xt, WtH, WtT, KHT_, KHT_, 0, 0, KHT_ / 64, 1,
        b_head, b_tail, hsB, tsB, nullptr, nullptr, seq);
    // bilinear v7: 768 blocks (32 m-tiles x 12 g x 2 i-halves), XCD-affine,
    // fragment-ordered streaming W, depth-4 prefetch, partial-slab epilogue
    k_bil<<<dim3(768), dim3(512), 0, stream>>>(hsB, tsB, WtB, logitsP);
    k_fin<<<(B_ * P_ * NL_ + 255) / 256, blk, 0, stream>>>(logitsP, b_bil, d_out, seq);
}